// Round 17
// baseline (432.088 us; speedup 1.0000x reference)
//
#include <hip/hip_runtime.h>

// Problem constants (from reference)
#define BATCH 2048
#define T 512
#define NF 10
#define HID 30
#define S3T 1536          // 3*T sequence length after reshape/transpose
#define FEAT_PER_B 15360  // 10*1536 features per batch element
// Workspace: BATCH * FEAT_PER_B * 2 = 62,914,560 bytes (f16 xpair)
// Layout: xpair[b][p][s][e] (p<5, s<1536, e<2) = f16 x[b][s][2p+e].
// One uint4 (16B) at stream p, chunk c = d-pair (2p,2p+1) for steps 4c..4c+3.

typedef float  v2f __attribute__((ext_vector_type(2)));
typedef _Float16 v2h __attribute__((ext_vector_type(2)));

#define LOG2E 1.44269504088896f

__device__ __forceinline__ float fexp(float x) {
    return __builtin_amdgcn_exp2f(x * LOG2E);   // v_exp_f32
}
__device__ __forceinline__ float frcp(float x) {
    return __builtin_amdgcn_rcpf(x);            // v_rcp_f32
}

// Packed f16 FMA with src1 half-BROADCAST via VOP3P op_sel (no repack movs):
//  blo: d.lo = a.lo*b.lo + d.lo ; d.hi = a.hi*b.lo + d.hi   (b low half x2)
//  bhi: d.lo = a.lo*b.hi + d.lo ; d.hi = a.hi*b.hi + d.hi   (b high half x2)
// Full-rate f16 packed math (2 cyc/wave64) vs half-rate fdot2 (4 cyc) — the
// r,z gates ride in {r_acc,z_acc} f16 accumulators (sigmoid slope <=0.25
// compresses the f16 accum error; n gate keeps f32 accum via fdot2).
__device__ __forceinline__ void pk_fma_blo(v2h& d, v2h a, v2h b) {
    asm("v_pk_fma_f16 %0, %1, %2, %0 op_sel:[0,0,0] op_sel_hi:[1,0,1]"
        : "+v"(d) : "v"(a), "v"(b));
}
__device__ __forceinline__ void pk_fma_bhi(v2h& d, v2h a, v2h b) {
    asm("v_pk_fma_f16 %0, %1, %2, %0 op_sel:[0,1,0] op_sel_hi:[1,1,1]"
        : "+v"(d) : "v"(a), "v"(b));
}

// Kernel 1: transpose-through-LDS [R15: 89 -> ~19us], f16 out [R16].
__global__ void __launch_bounds__(512)
feat_kernel(const int* __restrict__ atom_i,
            const int* __restrict__ atom_j,
            const float* __restrict__ dist,
            const float* __restrict__ emb,
            uint4* __restrict__ xpair8) {
    __shared__ float lf[512 * 31 + 30];   // slot(t,c) = t*31 + c
    const int b = blockIdx.x;
    const int t = threadIdx.x;

    {
        const int bt = b * T + t;
        const int ai = atom_i[bt];
        const int aj = atom_j[bt];
        const float dd = dist[bt];
        const float mi = (ai != 0) ? 1.0f : 0.0f;
        const float mj = (aj != 0) ? 1.0f : 0.0f;
        const float* ei = &emb[ai * NF];
        const float* ej = &emb[aj * NF];
        float* row = &lf[t * 31];
#pragma unroll
        for (int c = 0; c < NF; ++c) row[c] = mi * ei[c];
#pragma unroll
        for (int c = 0; c < NF; ++c) row[10 + c] = mj * ej[c];
#pragma unroll
        for (int c = 0; c < NF; ++c) {
            float ctr = (float)(c + 1) * 0.7f;
            float df = ctr - dd;
            row[20 + c] = mi * fexp(-df * df);
        }
    }
    __syncthreads();

    uint4* ob = xpair8 + (long)b * 1920;
    for (int o = t; o < 1920; o += 512) {
        unsigned p  = (unsigned)o / 384u;
        unsigned c4 = (unsigned)o - p * 384u;
        union { _Float16 h[8]; uint4 u; } pk;
#pragma unroll
        for (int kx = 0; kx < 8; ++kx) {
            unsigned s = 4u * c4 + (unsigned)(kx >> 1);
            unsigned e = (unsigned)(kx & 1);
            unsigned f = (2u * p + e) * 1536u + s;
            unsigned tt = f / 30u;            // compiler -> magic mul
            unsigned cc = f - tt * 30u;
            pk.h[kx] = (_Float16)lf[tt * 31u + cc];
        }
        ob[o] = pk.u;
    }
}

// One GRU step: reads hbuf16[PAR], writes hbuf16[PAR^1]. XQ = 5 uint4 chunk
// regs (4 steps of d-pairs); IDX in 0..3 selects the step's 32-bit word.
// r/z gates: 40 full-rate pk_fma_f16 into two split {r,z} accumulators
// (20 terms each — halves the f16 random walk), combined in f32.
// n gate: 20 half-rate fdot2, f32 accumulate (feeds h directly).
// Weights carry log2e prescale so every gate ends directly in exp2.
// Trailing wavefront fence replaces __syncthreads [R10: 576->420us].
#define STEP(PAR, XQ, IDX)                                                   \
    {                                                                        \
        const uint4* hv = (const uint4*)&hbuf16[PAR][half * 32];             \
        uint4 t0 = hv[0], t1 = hv[1], t2 = hv[2], t3 = hv[3];                \
        v2h hj[16];                                                          \
        __builtin_memcpy(&hj[0], &t0, 16);                                   \
        __builtin_memcpy(&hj[4], &t1, 16);                                   \
        __builtin_memcpy(&hj[8], &t2, 16);                                   \
        __builtin_memcpy(&hj[12], &t3, 16);                                  \
        v2h xc[5];                                                           \
        _Pragma("unroll")                                                    \
        for (int pp = 0; pp < 5; ++pp) {                                     \
            unsigned w = ((const unsigned*)&XQ[pp])[IDX];                    \
            __builtin_memcpy(&xc[pp], &w, 4);                                \
        }                                                                    \
        v2h a0 = brz_h;                 /* {r,z} acc 0 (bias-seeded) */      \
        v2h a1 = (v2h){(_Float16)0.0f, (_Float16)0.0f};                     \
        float ai = bif, ah = bhf;                                            \
        _Pragma("unroll")                                                    \
        for (int m = 0; m < 15; ++m) {                                       \
            pk_fma_blo(a0, wrz_hh[2 * m], hj[m]);                            \
            pk_fma_bhi(a1, wrz_hh[2 * m + 1], hj[m]);                        \
            ah = __builtin_amdgcn_fdot2(whn[m], hj[m], ah, false);           \
        }                                                                    \
        _Pragma("unroll")                                                    \
        for (int d = 0; d < 5; ++d) {                                        \
            pk_fma_blo(a0, wrz_ih[2 * d], xc[d]);                            \
            pk_fma_bhi(a1, wrz_ih[2 * d + 1], xc[d]);                        \
            ai = __builtin_amdgcn_fdot2(win[d], xc[d], ai, false);           \
        }                                                                    \
        float ar = (float)a0.x + (float)a1.x;                                \
        float az = (float)a0.y + (float)a1.y;                                \
        float er = __builtin_amdgcn_exp2f(ar);                               \
        float ez = __builtin_amdgcn_exp2f(az);                               \
        float rg = frcp(1.0f + er);                                          \
        float zg = frcp(1.0f + ez);                                          \
        float ng =                                                           \
            2.0f * frcp(1.0f + __builtin_amdgcn_exp2f(ai + rg * ah)) - 1.0f; \
        h = ng + zg * (h - ng);                                              \
        hbuf16[(PAR) ^ 1][half * 32 + k] = (_Float16)h;                      \
        __builtin_amdgcn_fence(__ATOMIC_ACQ_REL, "wavefront");               \
    }

// Kernel 2: GRU recurrence — full-dot mapping (R9+), 2 batches per wave,
// 1024 single-wave blocks. Lane k (k<30) computes the complete gates for
// unit k of its half's batch. h state stays f32 in registers; LDS broadcast
// copy is f16. amdgpu_waves_per_eu(1,1) [R6/R9]: pressure ceiling = the
// 1 wave/SIMD the grid supplies -> weights stay arch-resident.
__attribute__((amdgpu_waves_per_eu(1, 1)))
__global__ void __launch_bounds__(64)
gru_kernel(const _Float16* __restrict__ xpair,
           const float* __restrict__ W_ih,   // [90,10]
           const float* __restrict__ W_hh,   // [90,30]
           const float* __restrict__ b_ih,   // [90]
           const float* __restrict__ b_hh,   // [90]
           const float* __restrict__ W_out,  // [1,30]
           const float* __restrict__ b_out,  // [1]
           float* __restrict__ out) {
    __shared__ __align__(16) _Float16 hbuf16[2][64];
    const int lane = threadIdx.x;
    const int half = lane >> 5;
    const int k    = lane & 31;
    const bool active = (k < HID);
    const int kk = active ? k : (HID - 1);
    const int b = blockIdx.x * 2 + half;

    const float SRZ = -LOG2E;          // sigmoid(x) = rcp(1+exp2(-L x))
    const float SN  = -2.0f * LOG2E;   // tanh(u) = 2 rcp(1+exp2(-2L u)) - 1

    // r/z weights packed {wr_j, wz_j} per j (30 hh + 10 ih v2h regs);
    // n-gate weights as j-pairs for fdot2 (15 + 5). All log2e-prescaled.
    v2h wrz_hh[30], whn[15];
    {
        const float* Rr = &W_hh[(0 * HID + kk) * HID];
        const float* Rz = &W_hh[(1 * HID + kk) * HID];
        const float2* Rn = (const float2*)&W_hh[(2 * HID + kk) * HID];
#pragma unroll
        for (int j = 0; j < 30; ++j)
            wrz_hh[j] = (v2h){(_Float16)(Rr[j] * SRZ), (_Float16)(Rz[j] * SRZ)};
#pragma unroll
        for (int m = 0; m < 15; ++m) {
            float2 tn = Rn[m];
            whn[m] = (v2h){(_Float16)(tn.x * SN), (_Float16)(tn.y * SN)};
        }
    }
    v2h wrz_ih[10], win[5];
    {
        const float* Rr = &W_ih[(0 * HID + kk) * NF];
        const float* Rz = &W_ih[(1 * HID + kk) * NF];
        const float2* Rn = (const float2*)&W_ih[(2 * HID + kk) * NF];
#pragma unroll
        for (int d = 0; d < 10; ++d)
            wrz_ih[d] = (v2h){(_Float16)(Rr[d] * SRZ), (_Float16)(Rz[d] * SRZ)};
#pragma unroll
        for (int m = 0; m < 5; ++m) {
            float2 tn = Rn[m];
            win[m] = (v2h){(_Float16)(tn.x * SN), (_Float16)(tn.y * SN)};
        }
    }
    // Biases: r/z prescaled then f16-rounded (seeds acc0); n biases f32.
    const v2h brz_h = (v2h){
        (_Float16)(SRZ * (b_ih[0 * HID + kk] + b_hh[0 * HID + kk])),
        (_Float16)(SRZ * (b_ih[1 * HID + kk] + b_hh[1 * HID + kk]))};
    const float bif = SN * b_ih[2 * HID + kk];  // n biases stay split:
    const float bhf = SN * b_hh[2 * HID + kk];  // n uses ai + rg*ah

    const _Float16* xb = xpair + (long)b * FEAT_PER_B;
    const uint4* xa[5];
#pragma unroll
    for (int p = 0; p < 5; ++p) xa[p] = (const uint4*)(xb + p * 3072);

    hbuf16[0][lane] = (_Float16)0.0f;
    hbuf16[1][lane] = (_Float16)0.0f;
    __builtin_amdgcn_fence(__ATOMIC_ACQ_REL, "wavefront");

    float h = 0.0f;
    uint4 xq0[5], xq1[5];
#pragma unroll
    for (int p = 0; p < 5; ++p) xq0[p] = xa[p][0];

    // 384 chunks of 4 steps; prefetch distance 1 (clamped at the tail)
    for (int c = 0; c < 384; ++c) {
        const int cn = (c + 1 < 384) ? (c + 1) : c;
#pragma unroll
        for (int p = 0; p < 5; ++p) xq1[p] = xa[p][cn];
        STEP(0, xq0, 0);
        STEP(1, xq0, 1);
        STEP(0, xq0, 2);
        STEP(1, xq0, 3);
#pragma unroll
        for (int p = 0; p < 5; ++p) xq0[p] = xq1[p];
    }

    // out[b] = relu(h . W_out + b_out), reduced within each 32-lane half
    float v = active ? h * W_out[kk] : 0.0f;
#pragma unroll
    for (int off = 16; off; off >>= 1) v += __shfl_xor(v, off, 32);
    if (k == 0) {
        float o = v + b_out[0];
        out[b] = o > 0.0f ? o : 0.0f;
    }
}

extern "C" void kernel_launch(void* const* d_in, const int* in_sizes, int n_in,
                              void* d_out, int out_size, void* d_ws, size_t ws_size,
                              hipStream_t stream) {
    const int* atom_i   = (const int*)d_in[0];
    const int* atom_j   = (const int*)d_in[1];
    const float* dist   = (const float*)d_in[2];
    const float* emb    = (const float*)d_in[3];
    const float* W_ih   = (const float*)d_in[4];
    const float* W_hh   = (const float*)d_in[5];
    const float* b_ih   = (const float*)d_in[6];
    const float* b_hh   = (const float*)d_in[7];
    const float* W_out  = (const float*)d_in[8];
    const float* b_out  = (const float*)d_in[9];
    float* out = (float*)d_out;
    _Float16* xpair = (_Float16*)d_ws;   // 62,914,560 B

    feat_kernel<<<BATCH, 512, 0, stream>>>(atom_i, atom_j, dist, emb,
                                           (uint4*)xpair);
    gru_kernel<<<BATCH / 2, 64, 0, stream>>>(xpair, W_ih, W_hh, b_ih, b_hh,
                                             W_out, b_out, out);
}

// Round 18
// 388.987 us; speedup vs baseline: 1.1108x; 1.1108x over previous
//
#include <hip/hip_runtime.h>

// Problem constants (from reference)
#define BATCH 2048
#define T 512
#define NF 10
#define HID 30
#define S3T 1536          // 3*T sequence length after reshape/transpose
#define FEAT_PER_B 15360  // 10*1536 features per batch element
// Workspace: BATCH * FEAT_PER_B * 2 = 62,914,560 bytes (f16 xpair)
// Layout: xpair[b][p][s][e] (p<5, s<1536, e<2) = f16 x[b][s][2p+e].
// One uint4 (16B) at stream p, chunk c = d-pair (2p,2p+1) for steps 4c..4c+3.

typedef _Float16 v2h __attribute__((ext_vector_type(2)));

#define LOG2E 1.44269504088896f

__device__ __forceinline__ float fexp(float x) {
    return __builtin_amdgcn_exp2f(x * LOG2E);   // v_exp_f32
}
__device__ __forceinline__ float frcp(float x) {
    return __builtin_amdgcn_rcpf(x);            // v_rcp_f32
}

// R12/R16/R17 measured: fp32 scalar FMA, fp32 pk_fma, f16 fdot2, f16 pk_fma
// ALL deliver 2 MACs/lane per 2 issue cycles on the CDNA4 VALU -> the 120
// MAC/lane GRU step has an invariant 240 cyc/SIMD dot floor outside MFMA.
// fdot2 is kept: fewest instructions + f32 accumulate (absmax 9.8e-4).

// Kernel 1: transpose-through-LDS [R15: 89 -> ~19us], f16 out [R16].
__global__ void __launch_bounds__(512)
feat_kernel(const int* __restrict__ atom_i,
            const int* __restrict__ atom_j,
            const float* __restrict__ dist,
            const float* __restrict__ emb,
            uint4* __restrict__ xpair8) {
    __shared__ float lf[512 * 31 + 30];   // slot(t,c) = t*31 + c
    const int b = blockIdx.x;
    const int t = threadIdx.x;

    {
        const int bt = b * T + t;
        const int ai = atom_i[bt];
        const int aj = atom_j[bt];
        const float dd = dist[bt];
        const float mi = (ai != 0) ? 1.0f : 0.0f;
        const float mj = (aj != 0) ? 1.0f : 0.0f;
        const float* ei = &emb[ai * NF];
        const float* ej = &emb[aj * NF];
        float* row = &lf[t * 31];
#pragma unroll
        for (int c = 0; c < NF; ++c) row[c] = mi * ei[c];
#pragma unroll
        for (int c = 0; c < NF; ++c) row[10 + c] = mj * ej[c];
#pragma unroll
        for (int c = 0; c < NF; ++c) {
            float ctr = (float)(c + 1) * 0.7f;
            float df = ctr - dd;
            row[20 + c] = mi * fexp(-df * df);
        }
    }
    __syncthreads();

    uint4* ob = xpair8 + (long)b * 1920;
    for (int o = t; o < 1920; o += 512) {
        unsigned p  = (unsigned)o / 384u;
        unsigned c4 = (unsigned)o - p * 384u;
        union { _Float16 h[8]; uint4 u; } pk;
#pragma unroll
        for (int kx = 0; kx < 8; ++kx) {
            unsigned s = 4u * c4 + (unsigned)(kx >> 1);
            unsigned e = (unsigned)(kx & 1);
            unsigned f = (2u * p + e) * 1536u + s;
            unsigned tt = f / 30u;            // compiler -> magic mul
            unsigned cc = f - tt * 30u;
            pk.h[kx] = (_Float16)lf[tt * 31u + cc];
        }
        ob[o] = pk.u;
    }
}

// One GRU step: reads hbuf16[PAR], writes hbuf16[PAR^1]. XQ = 5 uint4 chunk
// regs (4 steps of d-pairs); IDX in 0..3 selects the step's 32-bit word
// (pure register aliasing). All 60 dots are v_dot2_f32_f16, f32 accumulate.
// Weights carry log2e prescale (r/z x(-L), n x(-2L)) so each gate ends
// directly in exp2. Trailing wavefront fence replaces __syncthreads
// [R10: 576->420us] — compile-time LDS ordering only, no vmcnt drain.
#define STEP(PAR, XQ, IDX)                                                   \
    {                                                                        \
        const uint4* hv = (const uint4*)&hbuf16[PAR][half * 32];             \
        uint4 t0 = hv[0], t1 = hv[1], t2 = hv[2], t3 = hv[3];                \
        v2h hj[16];                                                          \
        __builtin_memcpy(&hj[0], &t0, 16);                                   \
        __builtin_memcpy(&hj[4], &t1, 16);                                   \
        __builtin_memcpy(&hj[8], &t2, 16);                                   \
        __builtin_memcpy(&hj[12], &t3, 16);                                  \
        v2h xc[5];                                                           \
        _Pragma("unroll")                                                    \
        for (int pp = 0; pp < 5; ++pp) {                                     \
            unsigned w = ((const unsigned*)&XQ[pp])[IDX];                    \
            __builtin_memcpy(&xc[pp], &w, 4);                                \
        }                                                                    \
        float ar = brf, az = bzf, ai = bif, ah = bhf;                        \
        _Pragma("unroll")                                                    \
        for (int j = 0; j < 15; ++j) {                                       \
            ar = __builtin_amdgcn_fdot2(whr[j], hj[j], ar, false);           \
            az = __builtin_amdgcn_fdot2(whz[j], hj[j], az, false);           \
            ah = __builtin_amdgcn_fdot2(whn[j], hj[j], ah, false);           \
        }                                                                    \
        _Pragma("unroll")                                                    \
        for (int d = 0; d < 5; ++d) {                                        \
            ar = __builtin_amdgcn_fdot2(wir[d], xc[d], ar, false);           \
            az = __builtin_amdgcn_fdot2(wiz[d], xc[d], az, false);           \
            ai = __builtin_amdgcn_fdot2(win[d], xc[d], ai, false);           \
        }                                                                    \
        float er = __builtin_amdgcn_exp2f(ar);                               \
        float ez = __builtin_amdgcn_exp2f(az);                               \
        float rg = frcp(1.0f + er);                                          \
        float zg = frcp(1.0f + ez);                                          \
        float ng =                                                           \
            2.0f * frcp(1.0f + __builtin_amdgcn_exp2f(ai + rg * ah)) - 1.0f; \
        h = ng + zg * (h - ng);                                              \
        hbuf16[(PAR) ^ 1][half * 32 + k] = (_Float16)h;                      \
        __builtin_amdgcn_fence(__ATOMIC_ACQ_REL, "wavefront");               \
    }

// Kernel 2: GRU recurrence — full-dot mapping (R9+), 2 batches per wave,
// 1024 single-wave blocks. Lane k (k<30) computes the complete gates for
// unit k of its half's batch. h state stays f32 in registers; LDS broadcast
// copy is f16. amdgpu_waves_per_eu(1,1) [R6/R9]: pressure ceiling = the
// 1 wave/SIMD the grid supplies -> weights stay arch-resident.
// R18: ping-pong chunk loop (two chunks per iteration) eliminates the 20
// v_mov xq1->xq0 rotation (~10 cyc/step) of the R16 loop.
__attribute__((amdgpu_waves_per_eu(1, 1)))
__global__ void __launch_bounds__(64)
gru_kernel(const _Float16* __restrict__ xpair,
           const float* __restrict__ W_ih,   // [90,10]
           const float* __restrict__ W_hh,   // [90,30]
           const float* __restrict__ b_ih,   // [90]
           const float* __restrict__ b_hh,   // [90]
           const float* __restrict__ W_out,  // [1,30]
           const float* __restrict__ b_out,  // [1]
           float* __restrict__ out) {
    __shared__ __align__(16) _Float16 hbuf16[2][64];
    const int lane = threadIdx.x;
    const int half = lane >> 5;
    const int k    = lane & 31;
    const bool active = (k < HID);
    const int kk = active ? k : (HID - 1);
    const int b = blockIdx.x * 2 + half;

    const float SRZ = -LOG2E;          // sigmoid(x) = rcp(1+exp2(-L x))
    const float SN  = -2.0f * LOG2E;   // tanh(u) = 2 rcp(1+exp2(-2L u)) - 1

    // hh weights: 15 v2h (j-pairs) per gate, prescaled in f32 then RNE->f16.
    v2h whr[15], whz[15], whn[15];
    {
        const float2* Rr = (const float2*)&W_hh[(0 * HID + kk) * HID];
        const float2* Rz = (const float2*)&W_hh[(1 * HID + kk) * HID];
        const float2* Rn = (const float2*)&W_hh[(2 * HID + kk) * HID];
#pragma unroll
        for (int j = 0; j < 15; ++j) {
            float2 tr = Rr[j], tz = Rz[j], tn = Rn[j];
            whr[j] = (v2h){(_Float16)(tr.x * SRZ), (_Float16)(tr.y * SRZ)};
            whz[j] = (v2h){(_Float16)(tz.x * SRZ), (_Float16)(tz.y * SRZ)};
            whn[j] = (v2h){(_Float16)(tn.x * SN),  (_Float16)(tn.y * SN)};
        }
    }
    // ih weights: 5 v2h per gate (d-pairs match xpair layout).
    v2h wir[5], wiz[5], win[5];
    {
        const float2* Rr = (const float2*)&W_ih[(0 * HID + kk) * NF];
        const float2* Rz = (const float2*)&W_ih[(1 * HID + kk) * NF];
        const float2* Rn = (const float2*)&W_ih[(2 * HID + kk) * NF];
#pragma unroll
        for (int d = 0; d < 5; ++d) {
            float2 tr = Rr[d], tz = Rz[d], tn = Rn[d];
            wir[d] = (v2h){(_Float16)(tr.x * SRZ), (_Float16)(tr.y * SRZ)};
            wiz[d] = (v2h){(_Float16)(tz.x * SRZ), (_Float16)(tz.y * SRZ)};
            win[d] = (v2h){(_Float16)(tn.x * SN),  (_Float16)(tn.y * SN)};
        }
    }
    // Biases (prescaled, f32 — fdot2's accumulator seed).
    const float brf = SRZ * (b_ih[0 * HID + kk] + b_hh[0 * HID + kk]);
    const float bzf = SRZ * (b_ih[1 * HID + kk] + b_hh[1 * HID + kk]);
    const float bif = SN * b_ih[2 * HID + kk];  // n biases stay split:
    const float bhf = SN * b_hh[2 * HID + kk];  // n uses ai + rg*ah

    // 5 chunk streams: xa[p][c] = uint4 = d-pair (2p,2p+1), steps 4c..4c+3
    const _Float16* xb = xpair + (long)b * FEAT_PER_B;
    const uint4* xa[5];
#pragma unroll
    for (int p = 0; p < 5; ++p) xa[p] = (const uint4*)(xb + p * 3072);

    hbuf16[0][lane] = (_Float16)0.0f;
    hbuf16[1][lane] = (_Float16)0.0f;
    __builtin_amdgcn_fence(__ATOMIC_ACQ_REL, "wavefront");

    float h = 0.0f;
    uint4 xq0[5], xq1[5];
#pragma unroll
    for (int p = 0; p < 5; ++p) xq0[p] = xa[p][0];

    // 384 chunks of 4 steps, ping-pong pairs (xq0/xq1 alternate roles — no
    // register rotation). 384 is even; prefetch c2+1 is always in range,
    // tail prefetch c2+2 clamps to 383.
    for (int c2 = 0; c2 < 384; c2 += 2) {
#pragma unroll
        for (int p = 0; p < 5; ++p) xq1[p] = xa[p][c2 + 1];
        STEP(0, xq0, 0);
        STEP(1, xq0, 1);
        STEP(0, xq0, 2);
        STEP(1, xq0, 3);
        const int cn = (c2 + 2 < 384) ? (c2 + 2) : 383;
#pragma unroll
        for (int p = 0; p < 5; ++p) xq0[p] = xa[p][cn];
        STEP(0, xq1, 0);
        STEP(1, xq1, 1);
        STEP(0, xq1, 2);
        STEP(1, xq1, 3);
    }

    // out[b] = relu(h . W_out + b_out), reduced within each 32-lane half
    float v = active ? h * W_out[kk] : 0.0f;
#pragma unroll
    for (int off = 16; off; off >>= 1) v += __shfl_xor(v, off, 32);
    if (k == 0) {
        float o = v + b_out[0];
        out[b] = o > 0.0f ? o : 0.0f;
    }
}

extern "C" void kernel_launch(void* const* d_in, const int* in_sizes, int n_in,
                              void* d_out, int out_size, void* d_ws, size_t ws_size,
                              hipStream_t stream) {
    const int* atom_i   = (const int*)d_in[0];
    const int* atom_j   = (const int*)d_in[1];
    const float* dist   = (const float*)d_in[2];
    const float* emb    = (const float*)d_in[3];
    const float* W_ih   = (const float*)d_in[4];
    const float* W_hh   = (const float*)d_in[5];
    const float* b_ih   = (const float*)d_in[6];
    const float* b_hh   = (const float*)d_in[7];
    const float* W_out  = (const float*)d_in[8];
    const float* b_out  = (const float*)d_in[9];
    float* out = (float*)d_out;
    _Float16* xpair = (_Float16*)d_ws;   // 62,914,560 B

    feat_kernel<<<BATCH, 512, 0, stream>>>(atom_i, atom_j, dist, emb,
                                           (uint4*)xpair);
    gru_kernel<<<BATCH / 2, 64, 0, stream>>>(xpair, W_ih, W_hh, b_ih, b_hh,
                                             W_out, b_out, out);
}